// Round 3
// baseline (293.006 us; speedup 1.0000x reference)
//
#include <hip/hip_runtime.h>
#include <stdint.h>

typedef unsigned short u16;
typedef __bf16 bf16x8 __attribute__((ext_vector_type(8)));
typedef float f32x4 __attribute__((ext_vector_type(4)));

#define KDIM   768
#define MP     6400      // padded token-row count (50 * 128)
#define MREAL  6304      // 32 * 197
#define SLOT   ((size_t)MP * KDIM)
#define WSZ    ((size_t)KDIM * KDIM)
#define QSCALE_L 0.18033688011112042f   // 0.125 * log2(e): QK^T lands in log2 domain
#define BIGL     1.4426950e9f           // 1e9 * log2(e)

struct Ptr9 { const float* p[9]; };
struct Ptr7 { const float* p[7]; };

__device__ __forceinline__ u16 f2b(float f) {
  uint32_t x = __float_as_uint(f);
  x += 0x7FFFu + ((x >> 16) & 1u);   // RNE
  return (u16)(x >> 16);
}

__device__ __forceinline__ float b2f(u16 v) {
  return __uint_as_float(((uint32_t)v) << 16);
}

__device__ __forceinline__ void async16(const void* g, void* l) {
  __builtin_amdgcn_global_load_lds(
      (__attribute__((address_space(1))) void*)(uintptr_t)g,
      (__attribute__((address_space(3))) void*)l, 16, 0, 0);
}

// ---------------- fp32 -> bf16 conversion (x + 8 weight matrices) -------------
__global__ __launch_bounds__(256) void k_convert(Ptr9 src, u16* __restrict__ xb,
                                                 u16* __restrict__ wall) {
  const int XN4 = MREAL * KDIM / 4;
  const int WN4 = (int)(WSZ / 4);
  const int total = XN4 + 8 * WN4;
  for (int i = blockIdx.x * blockDim.x + threadIdx.x; i < total;
       i += gridDim.x * blockDim.x) {
    const float4* sp; ushort4* dp; int off;
    if (i < XN4) { sp = (const float4*)src.p[0]; dp = (ushort4*)xb; off = i; }
    else {
      int t = i - XN4; int slot = t / WN4; off = t - slot * WN4;
      sp = (const float4*)src.p[1 + slot];
      dp = (ushort4*)(wall + (size_t)slot * WSZ);
    }
    float4 v = sp[off];
    ushort4 u;
    u.x = f2b(v.x); u.y = f2b(v.y); u.z = f2b(v.z); u.w = f2b(v.w);
    dp[off] = u;
  }
}

// ---------------- bf16 MFMA GEMM: C = A @ W^T + bias -------------------------
__global__ __launch_bounds__(256) void k_gemm(const u16* __restrict__ A,
                                              const u16* __restrict__ W,
                                              Ptr7 bias,
                                              u16* __restrict__ outb,
                                              float* __restrict__ outf,
                                              float scale0, int guard) {
  __shared__ u16 As[128 * 32];
  __shared__ u16 Bs[128 * 32];
  const int tid = threadIdx.x;
  const int w = tid >> 6, lane = tid & 63;
  const int li = lane & 15, g = lane >> 4;
  const int brow = blockIdx.x, bcol = blockIdx.y, z = blockIdx.z;
  const u16* Wz = W + (size_t)z * WSZ;
  const float* bz = bias.p[z];
  const int wr = (w >> 1) * 64, wc = (w & 1) * 64;
  f32x4 acc[4][4] = {};

  for (int k0 = 0; k0 < KDIM; k0 += 32) {
    __syncthreads();
#pragma unroll
    for (int c = 0; c < 2; ++c) {
      int cbase = (c * 4 + w) * 64;
      int chunk = cbase + lane;
      int row = chunk >> 2, kg = chunk & 3;
      async16(A  + (size_t)(brow * 128 + row) * KDIM + k0 + kg * 8,
              (char*)As + cbase * 16);
      async16(Wz + (size_t)(bcol * 128 + row) * KDIM + k0 + kg * 8,
              (char*)Bs + cbase * 16);
    }
    asm volatile("s_waitcnt vmcnt(0)" ::: "memory");
    __syncthreads();

    bf16x8 af[4], bfr[4];
#pragma unroll
    for (int i = 0; i < 4; ++i) {
      af[i]  = *(const bf16x8*)(As + (wr + i * 16 + li) * 32 + g * 8);
      bfr[i] = *(const bf16x8*)(Bs + (wc + i * 16 + li) * 32 + g * 8);
    }
#pragma unroll
    for (int i = 0; i < 4; ++i)
#pragma unroll
      for (int j = 0; j < 4; ++j)
        acc[i][j] = __builtin_amdgcn_mfma_f32_16x16x32_bf16(af[i], bfr[j],
                                                            acc[i][j], 0, 0, 0);
  }

  const float scz = (z == 0) ? scale0 : 1.0f;
  if (outf == nullptr) {
    u16* O = outb + (size_t)z * SLOT;
#pragma unroll
    for (int j = 0; j < 4; ++j) {
      int col = bcol * 128 + wc + j * 16 + li;
      float bsv = bz[col];
#pragma unroll
      for (int i = 0; i < 4; ++i) {
        int row = brow * 128 + wr + i * 16 + g * 4;
#pragma unroll
        for (int r = 0; r < 4; ++r)
          O[(size_t)(row + r) * KDIM + col] = f2b((acc[i][j][r] + bsv) * scz);
      }
    }
  } else {
#pragma unroll
    for (int j = 0; j < 4; ++j) {
      int col = bcol * 128 + wc + j * 16 + li;
      float bsv = bz[col];
#pragma unroll
      for (int i = 0; i < 4; ++i) {
        int row = brow * 128 + wr + i * 16 + g * 4;
#pragma unroll
        for (int r = 0; r < 4; ++r)
          if (row + r < guard)
            outf[(size_t)(row + r) * KDIM + col] = acc[i][j][r] + bsv;
      }
    }
  }
}

// ---------------- fused 5-mask attention -------------------------------------
// Grid (12,32,4): h, b, tile-group. rt = bz*4+w (valid <= 12). Same-(b,h)
// blocks are 384 apart in dispatch id (384%8==0 -> same XCD L2 slice).
// K staged via global_load_lds with inverse-swizzled SOURCE (linear LDS dest),
// read back with XOR-swizzled ds_read_b128. Single KL buffer; mask m+1's
// async loads issued after the post-QK barrier, hidden under softmax+PV.
// Identity mask (m=4) collapsed analytically: rows i>=1 get oacc += V[i];
// only the rt==0 wave (CLS row) runs the full m=4 path.
__global__ __launch_bounds__(256, 2) void k_attn(const u16* __restrict__ qkv,
                                                 u16* __restrict__ att) {
  __shared__ u16 KL[208 * 64];      // 26.0 KB; chunk c holds global chunk c^(row&7)
  __shared__ u16 VT[64][228];       // 28.5 KB; V^T, cols 197..227 zeroed
  __shared__ u16 P[2][4][16][36];   //  9.0 KB; lag-1 rotated per-wave P chunk
  const int tid = threadIdx.x;
  const int w = tid >> 6, lane = tid & 63;
  const int li = lane & 15, g = lane >> 4;
  const int h = blockIdx.x, b = blockIdx.y, bz = blockIdx.z;
  const int rt = bz * 4 + w;
  const size_t rowbase = (size_t)b * 197;
  const int cb = h * 64;
  const u16* Q = qkv;
  const u16* V = qkv + 6 * SLOT;
  const bool task = (rt <= 12);
  const int nmask = (bz == 0) ? 5 : 4;

  // --- K staging: 1664 chunks of 16B; wave w covers bases (i*4+w)*64 ---------
  auto stageK = [&](int m) {
    const u16* Kg = qkv + (size_t)(1 + m) * SLOT;
#pragma unroll
    for (int i = 0; i < 7; ++i) {
      int cb64 = (i * 4 + w) * 64;
      if (cb64 >= 1664) break;                 // wave-uniform
      int c = cb64 + lane;
      int row = c >> 3;
      int kg = (c & 7) ^ (row & 7);            // inverse swizzle on SOURCE
      async16(Kg + (rowbase + row) * KDIM + cb + kg * 8,
              (char*)KL + cb64 * 16);
    }
  };

  stageK(0);

  // stage V^T (global coalesced reads, scalar transpose writes)
  for (int e = tid; e < 64 * 228; e += 256) {
    int j = e >> 6, d = e & 63;
    u16 val = 0;
    if (j < 197) val = V[(rowbase + j) * KDIM + cb + d];
    VT[d][j] = val;
  }

  // per-lane i-side mask state
  const int i_ = rt * 16 + li;
  const int pi = i_ - 1;
  const int ri = pi / 14, ci = pi % 14;
  const bool i0 = (i_ == 0);

  int cj0[13], rj0[13];
#pragma unroll
  for (int t = 0; t < 13; ++t) {
    int pj = t * 16 + g * 4 - 1;
    rj0[t] = pj / 14; cj0[t] = pj % 14;
  }

  bf16x8 qa0, qa1;
  {
    const size_t qrow = rowbase + (size_t)rt * 16 + li;   // < SLOT rows, finite
    qa0 = *(const bf16x8*)(Q + qrow * KDIM + cb + g * 8);
    qa1 = *(const bf16x8*)(Q + qrow * KDIM + cb + 32 + g * 8);
  }

  f32x4 oacc[4] = {};

  for (int m = 0; m < nmask; ++m) {
    asm volatile("s_waitcnt vmcnt(0)" ::: "memory");  // own K loads done
    __syncthreads();                                   // everyone's done + VT ready

    const bool doit = task && (m < 4 || rt == 0);
    f32x4 s[13];
    if (doit) {
      // QK^T from swizzled KL, swapped operands: lane holds S^T[j][i=li]
#pragma unroll
      for (int t = 0; t < 13; ++t) {
        const char* base = (const char*)KL + (size_t)(t * 16 + li) * 128;
        const int sw = (li & 7) << 4;
        bf16x8 kb0 = *(const bf16x8*)(base + ((g * 16) ^ sw));
        bf16x8 kb1 = *(const bf16x8*)(base + ((64 + g * 16) ^ sw));
        f32x4 zz = {};
        zz = __builtin_amdgcn_mfma_f32_16x16x32_bf16(kb0, qa0, zz, 0, 0, 0);
        zz = __builtin_amdgcn_mfma_f32_16x16x32_bf16(kb1, qa1, zz, 0, 0, 0);
        s[t] = zz;
      }
    }
    __syncthreads();                     // all waves done reading KL
    if (m + 1 < nmask) stageK(m + 1);    // async overwrite, hidden under below

    if (doit) {
      // analytic mask (log2 domain) + lane-local max
      float mx = -3.0e38f;
#pragma unroll
      for (int t = 0; t < 13; ++t) {
        int jv = t * 16 + g * 4;
        int cjr = cj0[t], rjr = rj0[t];
#pragma unroll
        for (int r = 0; r < 4; ++r) {
          bool mk;
          if (m == 0)      mk = ci < cjr;    // left
          else if (m == 1) mk = ci > cjr;    // right
          else if (m == 2) mk = ri < rjr;    // up
          else if (m == 3) mk = ri > rjr;    // down
          else             mk = (i_ == jv);  // ident (rt==0 wave only)
          if (i0 | (jv == 0)) mk = false;    // CLS row/col
          float sv = s[t][r] - (mk ? 0.f : BIGL);
          if (jv >= 197) sv = -3.0e38f;      // pad cols: hard kill
          s[t][r] = sv;
          mx = fmaxf(mx, sv);
          ++jv; ++cjr; if (cjr == 14) { cjr = 0; ++rjr; }
        }
      }
      mx = fmaxf(mx, __shfl_xor(mx, 16));
      mx = fmaxf(mx, __shfl_xor(mx, 32));
      float sum = 0.f;
#pragma unroll
      for (int t = 0; t < 13; ++t)
#pragma unroll
        for (int r = 0; r < 4; ++r) {
          float e_ = exp2f(s[t][r] - mx);
          s[t][r] = e_;
          sum += e_;
        }
      sum += __shfl_xor(sum, 16);
      sum += __shfl_xor(sum, 32);
      const float inv = 1.0f / sum;

      // PV: lag-1 pack-ahead through rotating P buffers
#pragma unroll
      for (int kt = 0; kt <= 7; ++kt) {
        if (kt < 7) {
#pragma unroll
          for (int h2 = 0; h2 < 2; ++h2) {
            const int t = kt * 2 + h2;
            uint32_t w0 = 0, w1 = 0;
            if (t < 13) {
              float a0 = s[t][0] * inv, a1 = s[t][1] * inv;
              float a2 = s[t][2] * inv, a3 = s[t][3] * inv;
              asm("v_cvt_pk_bf16_f32 %0, %1, %2" : "=v"(w0) : "v"(a0), "v"(a1));
              asm("v_cvt_pk_bf16_f32 %0, %1, %2" : "=v"(w1) : "v"(a2), "v"(a3));
            }
            uint2 pw; pw.x = w0; pw.y = w1;
            *(uint2*)&P[kt & 1][w][li][h2 * 16 + g * 4] = pw;
          }
        }
        if (kt > 0) {
          const int kr = kt - 1;
          bf16x8 pa = *(const bf16x8*)&P[kr & 1][w][li][g * 8];
#pragma unroll
          for (int dt = 0; dt < 4; ++dt) {
            bf16x8 vb = *(const bf16x8*)&VT[dt * 16 + li][kr * 32 + g * 8];
            oacc[dt] = __builtin_amdgcn_mfma_f32_16x16x32_bf16(pa, vb, oacc[dt],
                                                               0, 0, 0);
          }
        }
      }
    }
  }

  // identity-mask contribution for non-CLS rows: P is exactly one-hot -> +V[i]
  if (task && rt > 0) {
#pragma unroll
    for (int dt = 0; dt < 4; ++dt)
#pragma unroll
      for (int r = 0; r < 4; ++r) {
        int i2 = rt * 16 + g * 4 + r;          // >=16; cols >=197 are zero
        oacc[dt][r] += b2f(VT[dt * 16 + li][i2]);
      }
  }

  if (task) {
#pragma unroll
    for (int dt = 0; dt < 4; ++dt)
#pragma unroll
      for (int r = 0; r < 4; ++r) {
        int i2 = rt * 16 + g * 4 + r;
        if (i2 < 197)
          att[(rowbase + i2) * KDIM + cb + dt * 16 + li] = f2b(oacc[dt][r]);
      }
  }
}

// -----------------------------------------------------------------------------
extern "C" void kernel_launch(void* const* d_in, const int* in_sizes, int n_in,
                              void* d_out, int out_size, void* d_ws, size_t ws_size,
                              hipStream_t stream) {
  (void)in_sizes; (void)n_in; (void)out_size; (void)ws_size;
  const float* x      = (const float*)d_in[0];
  const float* q_w    = (const float*)d_in[1];
  const float* q_b    = (const float*)d_in[2];
  const float* kA_w   = (const float*)d_in[3];
  const float* kA_b   = (const float*)d_in[4];
  const float* kB_w   = (const float*)d_in[5];
  const float* kB_b   = (const float*)d_in[6];
  const float* kC_w   = (const float*)d_in[7];
  const float* kC_b   = (const float*)d_in[8];
  const float* kD_w   = (const float*)d_in[9];
  const float* kD_b   = (const float*)d_in[10];
  const float* kE_w   = (const float*)d_in[11];
  const float* kE_b   = (const float*)d_in[12];
  const float* v_w    = (const float*)d_in[13];
  const float* v_b    = (const float*)d_in[14];
  const float* proj_w = (const float*)d_in[15];
  const float* proj_b = (const float*)d_in[16];
  float* out = (float*)d_out;

  u16* xb   = (u16*)d_ws;                 // SLOT
  u16* qkv  = xb + SLOT;                  // 7 * SLOT
  u16* wall = qkv + 7 * SLOT;             // 8 * WSZ
  u16* att  = xb;                         // reuse after gemm1 consumed x_b

  Ptr9 cs;
  cs.p[0] = x;    cs.p[1] = q_w;  cs.p[2] = kA_w; cs.p[3] = kB_w;
  cs.p[4] = kC_w; cs.p[5] = kD_w; cs.p[6] = kE_w; cs.p[7] = v_w;
  cs.p[8] = proj_w;
  k_convert<<<dim3(2048), dim3(256), 0, stream>>>(cs, xb, wall);

  Ptr7 b1;
  b1.p[0] = q_b;  b1.p[1] = kA_b; b1.p[2] = kB_b; b1.p[3] = kC_b;
  b1.p[4] = kD_b; b1.p[5] = kE_b; b1.p[6] = v_b;
  k_gemm<<<dim3(50, 6, 7), dim3(256), 0, stream>>>(xb, wall, b1, qkv, nullptr,
                                                   QSCALE_L, 0);

  k_attn<<<dim3(12, 32, 4), dim3(256), 0, stream>>>(qkv, att);

  Ptr7 b2;
  for (int i = 0; i < 7; ++i) b2.p[i] = proj_b;
  k_gemm<<<dim3(50, 6, 1), dim3(256), 0, stream>>>(att, wall + 7 * WSZ, b2,
                                                   nullptr, out, 1.0f, MREAL);
}

// Round 5
// 241.665 us; speedup vs baseline: 1.2124x; 1.2124x over previous
//
#include <hip/hip_runtime.h>
#include <stdint.h>

typedef unsigned short u16;
typedef __bf16 bf16x8 __attribute__((ext_vector_type(8)));
typedef float f32x4 __attribute__((ext_vector_type(4)));

#define KDIM   768
#define MP     6400      // padded token-row count (50 * 128)
#define MREAL  6304      // 32 * 197
#define SLOT   ((size_t)MP * KDIM)
#define WSZ    ((size_t)KDIM * KDIM)
#define QSCALE_L 0.18033688011112042f   // 0.125 * log2(e): QK^T lands in log2 domain
#define BIGL     1.4426950e9f           // 1e9 * log2(e)

struct Ptr9 { const float* p[9]; };
struct Ptr7 { const float* p[7]; };

__device__ __forceinline__ u16 f2b(float f) {
  uint32_t x = __float_as_uint(f);
  x += 0x7FFFu + ((x >> 16) & 1u);   // RNE
  return (u16)(x >> 16);
}

__device__ __forceinline__ float b2f(u16 v) {
  return __uint_as_float(((uint32_t)v) << 16);
}

__device__ __forceinline__ void async16(const void* g, void* l) {
  __builtin_amdgcn_global_load_lds(
      (__attribute__((address_space(1))) void*)(uintptr_t)g,
      (__attribute__((address_space(3))) void*)l, 16, 0, 0);
}

// ---------------- fp32 -> bf16 conversion (x + 8 weight matrices) -------------
__global__ __launch_bounds__(256) void k_convert(Ptr9 src, u16* __restrict__ xb,
                                                 u16* __restrict__ wall) {
  const int XN4 = MREAL * KDIM / 4;
  const int WN4 = (int)(WSZ / 4);
  const int total = XN4 + 8 * WN4;
  for (int i = blockIdx.x * blockDim.x + threadIdx.x; i < total;
       i += gridDim.x * blockDim.x) {
    const float4* sp; ushort4* dp; int off;
    if (i < XN4) { sp = (const float4*)src.p[0]; dp = (ushort4*)xb; off = i; }
    else {
      int t = i - XN4; int slot = t / WN4; off = t - slot * WN4;
      sp = (const float4*)src.p[1 + slot];
      dp = (ushort4*)(wall + (size_t)slot * WSZ);
    }
    float4 v = sp[off];
    ushort4 u;
    u.x = f2b(v.x); u.y = f2b(v.y); u.z = f2b(v.z); u.w = f2b(v.w);
    dp[off] = u;
  }
}

// ---------------- bf16 MFMA GEMM: C = A @ W^T + bias -------------------------
__global__ __launch_bounds__(256) void k_gemm(const u16* __restrict__ A,
                                              const u16* __restrict__ W,
                                              Ptr7 bias,
                                              u16* __restrict__ outb,
                                              float* __restrict__ outf,
                                              float scale0, int guard) {
  __shared__ u16 As[128 * 32];
  __shared__ u16 Bs[128 * 32];
  const int tid = threadIdx.x;
  const int w = tid >> 6, lane = tid & 63;
  const int li = lane & 15, g = lane >> 4;
  const int brow = blockIdx.x, bcol = blockIdx.y, z = blockIdx.z;
  const u16* Wz = W + (size_t)z * WSZ;
  const float* bz = bias.p[z];
  const int wr = (w >> 1) * 64, wc = (w & 1) * 64;
  f32x4 acc[4][4] = {};

  for (int k0 = 0; k0 < KDIM; k0 += 32) {
    __syncthreads();
#pragma unroll
    for (int c = 0; c < 2; ++c) {
      int cbase = (c * 4 + w) * 64;
      int chunk = cbase + lane;
      int row = chunk >> 2, kg = chunk & 3;
      async16(A  + (size_t)(brow * 128 + row) * KDIM + k0 + kg * 8,
              (char*)As + cbase * 16);
      async16(Wz + (size_t)(bcol * 128 + row) * KDIM + k0 + kg * 8,
              (char*)Bs + cbase * 16);
    }
    asm volatile("s_waitcnt vmcnt(0)" ::: "memory");
    __syncthreads();

    bf16x8 af[4], bfr[4];
#pragma unroll
    for (int i = 0; i < 4; ++i) {
      af[i]  = *(const bf16x8*)(As + (wr + i * 16 + li) * 32 + g * 8);
      bfr[i] = *(const bf16x8*)(Bs + (wc + i * 16 + li) * 32 + g * 8);
    }
#pragma unroll
    for (int i = 0; i < 4; ++i)
#pragma unroll
      for (int j = 0; j < 4; ++j)
        acc[i][j] = __builtin_amdgcn_mfma_f32_16x16x32_bf16(af[i], bfr[j],
                                                            acc[i][j], 0, 0, 0);
  }

  const float scz = (z == 0) ? scale0 : 1.0f;
  if (outf == nullptr) {
    u16* O = outb + (size_t)z * SLOT;
#pragma unroll
    for (int j = 0; j < 4; ++j) {
      int col = bcol * 128 + wc + j * 16 + li;
      float bsv = bz[col];
#pragma unroll
      for (int i = 0; i < 4; ++i) {
        int row = brow * 128 + wr + i * 16 + g * 4;
#pragma unroll
        for (int r = 0; r < 4; ++r)
          O[(size_t)(row + r) * KDIM + col] = f2b((acc[i][j][r] + bsv) * scz);
      }
    }
  } else {
#pragma unroll
    for (int j = 0; j < 4; ++j) {
      int col = bcol * 128 + wc + j * 16 + li;
      float bsv = bz[col];
#pragma unroll
      for (int i = 0; i < 4; ++i) {
        int row = brow * 128 + wr + i * 16 + g * 4;
#pragma unroll
        for (int r = 0; r < 4; ++r)
          if (row + r < guard)
            outf[(size_t)(row + r) * KDIM + col] = acc[i][j][r] + bsv;
      }
    }
  }
}

// ---------------- fused 5-mask attention -------------------------------------
// Grid (2,12,32) = (tile-group, h, b); block = 8 waves (512 thr), wave w owns
// row-tile rt = bx*8 + w (valid <= 12). Adjacent blocks share (b,h) K/V -> L2.
// K staged via global_load_lds with inverse-swizzled SOURCE (linear LDS dest),
// read back with XOR-swizzled ds_read_b128. Mask m+1's loads issued after the
// post-QK barrier, hidden under softmax+PV. Identity mask collapsed to +V[i]
// for rows i>=1; only the rt==0 wave runs the full m=4 path.
// Softmax core = round-3's validated numerics (mask-add -BIGL pre-max,
// hard pad-kill pre-max, post-mask max, exp2f, IEEE 1/sum).
__global__ __launch_bounds__(512, 4) void k_attn(const u16* __restrict__ qkv,
                                                 u16* __restrict__ att) {
  __shared__ u16 KL[208 * 64];      // 26.0 KB; chunk c holds global chunk c^(row&7)
  __shared__ u16 VT[64][228];       // 28.5 KB; V^T, cols 197..227 zeroed
  __shared__ u16 P[2][8][16][36];   // 18.0 KB; lag-1 rotated per-wave P chunk
  const int tid = threadIdx.x;
  const int w = tid >> 6, lane = tid & 63;
  const int li = lane & 15, g = lane >> 4;
  const int bx = blockIdx.x, h = blockIdx.y, b = blockIdx.z;
  const int rt = bx * 8 + w;
  const size_t rowbase = (size_t)b * 197;
  const int cb = h * 64;
  const u16* Q = qkv;
  const u16* V = qkv + 6 * SLOT;
  const bool task = (rt <= 12);
  const int nmask = (bx == 0) ? 5 : 4;

  // --- K staging: 1664 16B-chunks; wave w covers bases (i*8+w)*64 ------------
  auto stageK = [&](int m) {
    const u16* Kg = qkv + (size_t)(1 + m) * SLOT;
#pragma unroll
    for (int i = 0; i < 4; ++i) {
      int cb64 = (i * 8 + w) * 64;
      if (cb64 >= 1664) break;                 // wave-uniform
      int c = cb64 + lane;
      int row = c >> 3;
      int kg = (c & 7) ^ (row & 7);            // inverse swizzle on SOURCE
      async16(Kg + (rowbase + row) * KDIM + cb + kg * 8,
              (char*)KL + cb64 * 16);
    }
  };

  stageK(0);

  // stage V^T (global coalesced reads, scalar transpose writes)
  for (int e = tid; e < 64 * 228; e += 512) {
    int j = e >> 6, d = e & 63;
    u16 val = 0;
    if (j < 197) val = V[(rowbase + j) * KDIM + cb + d];
    VT[d][j] = val;
  }

  // per-lane i-side mask state
  const int i_ = rt * 16 + li;
  const int pi = i_ - 1;
  const int ri = pi / 14, ci = pi % 14;
  const bool i0 = (i_ == 0);

  // running j-side seed at (t=0, r=0): pj = g*4 - 1
  const int rs_init = (g * 4 - 1) / 14;        // 0 (g=0 gives -1/14 == 0)
  const int cs_init = (g * 4 - 1) % 14;        // -1, 3, 7, 11

  bf16x8 qa0, qa1;
  {
    const size_t qrow = rowbase + (size_t)rt * 16 + li;   // < MP rows, finite
    qa0 = *(const bf16x8*)(Q + qrow * KDIM + cb + g * 8);
    qa1 = *(const bf16x8*)(Q + qrow * KDIM + cb + 32 + g * 8);
  }

  f32x4 oacc[4] = {};

  for (int m = 0; m < nmask; ++m) {
    asm volatile("s_waitcnt vmcnt(0)" ::: "memory");  // own K loads done
    __syncthreads();                                   // all loads + VT ready

    const bool doit = task && (m < 4 || rt == 0);
    f32x4 s[13];
    if (doit) {
      // QK^T from swizzled KL, swapped operands: lane holds S^T[j][i=li]
      __builtin_amdgcn_s_setprio(1);
#pragma unroll
      for (int t = 0; t < 13; ++t) {
        const char* base = (const char*)KL + (size_t)(t * 16 + li) * 128;
        const int sw = (li & 7) << 4;
        bf16x8 kb0 = *(const bf16x8*)(base + ((g * 16) ^ sw));
        bf16x8 kb1 = *(const bf16x8*)(base + ((64 + g * 16) ^ sw));
        f32x4 zz = {};
        zz = __builtin_amdgcn_mfma_f32_16x16x32_bf16(kb0, qa0, zz, 0, 0, 0);
        zz = __builtin_amdgcn_mfma_f32_16x16x32_bf16(kb1, qa1, zz, 0, 0, 0);
        s[t] = zz;
      }
      __builtin_amdgcn_s_setprio(0);
    }
    __syncthreads();                     // all waves done reading KL
    if (m + 1 < nmask) stageK(m + 1);    // async overwrite, hidden under below

    if (doit) {
      // analytic mask (log2 domain, R3 numerics) + post-mask lane-local max
      float mx = -3.0e38f;
      int cs = cs_init, rs = rs_init;
#pragma unroll
      for (int t = 0; t < 13; ++t) {
        int jv = t * 16 + g * 4;
        int cjr = cs, rjr = rs;
#pragma unroll
        for (int r = 0; r < 4; ++r) {
          bool mk;
          if (m == 0)      mk = ci < cjr;    // left
          else if (m == 1) mk = ci > cjr;    // right
          else if (m == 2) mk = ri < rjr;    // up
          else if (m == 3) mk = ri > rjr;    // down
          else             mk = (i_ == jv);  // ident (rt==0 wave only)
          if (i0 | (jv == 0)) mk = false;    // CLS row/col: uniform -BIG shift
          float sv = s[t][r] - (mk ? 0.f : BIGL);
          if (jv >= 197) sv = -3.0e38f;      // pad cols: hard kill (NaN-safe)
          s[t][r] = sv;
          mx = fmaxf(mx, sv);
          ++jv; ++cjr; if (cjr == 14) { cjr = 0; ++rjr; }
        }
        cs += 2; ++rs; if (cs >= 14) { cs -= 14; ++rs; }   // seed advance (+16)
      }
      mx = fmaxf(mx, __shfl_xor(mx, 16));
      mx = fmaxf(mx, __shfl_xor(mx, 32));
      float sum = 0.f;
#pragma unroll
      for (int t = 0; t < 13; ++t)
#pragma unroll
        for (int r = 0; r < 4; ++r) {
          float e_ = exp2f(s[t][r] - mx);
          s[t][r] = e_;
          sum += e_;
        }
      sum += __shfl_xor(sum, 16);
      sum += __shfl_xor(sum, 32);
      const float inv = 1.0f / sum;

      // PV: lag-1 pack-ahead through rotating P buffers
#pragma unroll
      for (int kt = 0; kt <= 7; ++kt) {
        if (kt < 7) {
#pragma unroll
          for (int h2 = 0; h2 < 2; ++h2) {
            const int t = kt * 2 + h2;
            uint32_t w0 = 0, w1 = 0;
            if (t < 13) {
              float a0 = s[t][0] * inv, a1 = s[t][1] * inv;
              float a2 = s[t][2] * inv, a3 = s[t][3] * inv;
              asm("v_cvt_pk_bf16_f32 %0, %1, %2" : "=v"(w0) : "v"(a0), "v"(a1));
              asm("v_cvt_pk_bf16_f32 %0, %1, %2" : "=v"(w1) : "v"(a2), "v"(a3));
            }
            uint2 pw; pw.x = w0; pw.y = w1;
            *(uint2*)&P[kt & 1][w][li][h2 * 16 + g * 4] = pw;
          }
        }
        if (kt > 0) {
          const int kr = kt - 1;
          bf16x8 pa = *(const bf16x8*)&P[kr & 1][w][li][g * 8];
          __builtin_amdgcn_s_setprio(1);
#pragma unroll
          for (int dt = 0; dt < 4; ++dt) {
            bf16x8 vb = *(const bf16x8*)&VT[dt * 16 + li][kr * 32 + g * 8];
            oacc[dt] = __builtin_amdgcn_mfma_f32_16x16x32_bf16(pa, vb, oacc[dt],
                                                               0, 0, 0);
          }
          __builtin_amdgcn_s_setprio(0);
        }
      }
    }
  }

  // identity-mask contribution for non-CLS rows: P is exactly one-hot -> +V[i]
  if (task && rt > 0) {
#pragma unroll
    for (int dt = 0; dt < 4; ++dt)
#pragma unroll
      for (int r = 0; r < 4; ++r) {
        int i2 = rt * 16 + g * 4 + r;          // >=16; cols >=197 are zero
        oacc[dt][r] += b2f(VT[dt * 16 + li][i2]);
      }
  }

  if (task) {
#pragma unroll
    for (int dt = 0; dt < 4; ++dt)
#pragma unroll
      for (int r = 0; r < 4; ++r) {
        int i2 = rt * 16 + g * 4 + r;
        if (i2 < 197)
          att[(rowbase + i2) * KDIM + cb + dt * 16 + li] = f2b(oacc[dt][r]);
      }
  }
}

// -----------------------------------------------------------------------------
extern "C" void kernel_launch(void* const* d_in, const int* in_sizes, int n_in,
                              void* d_out, int out_size, void* d_ws, size_t ws_size,
                              hipStream_t stream) {
  (void)in_sizes; (void)n_in; (void)out_size; (void)ws_size;
  const float* x      = (const float*)d_in[0];
  const float* q_w    = (const float*)d_in[1];
  const float* q_b    = (const float*)d_in[2];
  const float* kA_w   = (const float*)d_in[3];
  const float* kA_b   = (const float*)d_in[4];
  const float* kB_w   = (const float*)d_in[5];
  const float* kB_b   = (const float*)d_in[6];
  const float* kC_w   = (const float*)d_in[7];
  const float* kC_b   = (const float*)d_in[8];
  const float* kD_w   = (const float*)d_in[9];
  const float* kD_b   = (const float*)d_in[10];
  const float* kE_w   = (const float*)d_in[11];
  const float* kE_b   = (const float*)d_in[12];
  const float* v_w    = (const float*)d_in[13];
  const float* v_b    = (const float*)d_in[14];
  const float* proj_w = (const float*)d_in[15];
  const float* proj_b = (const float*)d_in[16];
  float* out = (float*)d_out;

  u16* xb   = (u16*)d_ws;                 // SLOT
  u16* qkv  = xb + SLOT;                  // 7 * SLOT
  u16* wall = qkv + 7 * SLOT;             // 8 * WSZ
  u16* att  = xb;                         // reuse after gemm1 consumed x_b

  Ptr9 cs;
  cs.p[0] = x;    cs.p[1] = q_w;  cs.p[2] = kA_w; cs.p[3] = kB_w;
  cs.p[4] = kC_w; cs.p[5] = kD_w; cs.p[6] = kE_w; cs.p[7] = v_w;
  cs.p[8] = proj_w;
  k_convert<<<dim3(2048), dim3(256), 0, stream>>>(cs, xb, wall);

  Ptr7 b1;
  b1.p[0] = q_b;  b1.p[1] = kA_b; b1.p[2] = kB_b; b1.p[3] = kC_b;
  b1.p[4] = kD_b; b1.p[5] = kE_b; b1.p[6] = v_b;
  k_gemm<<<dim3(50, 6, 7), dim3(256), 0, stream>>>(xb, wall, b1, qkv, nullptr,
                                                   QSCALE_L, 0);

  k_attn<<<dim3(2, 12, 32), dim3(512), 0, stream>>>(qkv, att);

  Ptr7 b2;
  for (int i = 0; i < 7; ++i) b2.p[i] = proj_b;
  k_gemm<<<dim3(50, 6, 1), dim3(256), 0, stream>>>(att, wall + 7 * WSZ, b2,
                                                   nullptr, out, 1.0f, MREAL);
}